// Round 5
// baseline (382.854 us; speedup 1.0000x reference)
//
#include <hip/hip_runtime.h>

// Problem constants (match reference)
constexpr int Bn = 4, Cn = 512, Ln = 2048, CIn = 512, Hn = 8, Dn = 64;
constexpr int COn = 3 * CIn;  // 1536 stacked output channels: [theta; phi; g]

typedef unsigned short u16;
typedef unsigned int u32;
typedef __attribute__((ext_vector_type(8))) short bfrag;  // 8 x bf16 (4 VGPRs)
typedef __attribute__((ext_vector_type(4))) float facc;   // 4 x f32 acc

// 1/sqrt(D) * log2(e): folded into theta weights/bias so QK^T lands in log2 domain
#define SCF 0.180336879f

__device__ __forceinline__ facc mfma16(bfrag a, bfrag b, facc c) {
  return __builtin_amdgcn_mfma_f32_16x16x32_bf16(a, b, c, 0, 0, 0);
}

__device__ __forceinline__ void async16(const void* g, void* l) {
  __builtin_amdgcn_global_load_lds((const __attribute__((address_space(1))) void*)g,
                                   (__attribute__((address_space(3))) void*)l, 16, 0, 0);
}

__device__ __forceinline__ u16 f2bf(float x) {  // RNE float->bf16
  union { float f; u32 u; } v; v.f = x;
  u32 r = v.u + 0x7FFFu + ((v.u >> 16) & 1u);
  return (u16)(r >> 16);
}

__device__ __forceinline__ u16 f2bf_fast(float x) {  // round-half-up, 2 ops
  union { float f; u32 u; } v; v.f = x;
  return (u16)((v.u + 0x8000u) >> 16);
}

// pack 2 floats -> bf16x2 in one u32: 2 round-adds + 1 v_perm
__device__ __forceinline__ u32 pkbf(float lof, float hif) {
  union { float f; u32 u; } a, b; a.f = lof; b.f = hif;
  return __builtin_amdgcn_perm(b.u + 0x8000u, a.u + 0x8000u, 0x07060302u);
}

__device__ __forceinline__ float bflo(u32 u) { return __uint_as_float(u << 16); }
__device__ __forceinline__ float bfhi(u32 u) { return __uint_as_float(u & 0xFFFF0000u); }

// Swizzled frag reads. fr8: row stride 64 u16 (128B, 8 granules, xor row&7).
// fr4: row stride 32 u16 (64B, 4 granules, xor row&3). Conflict-free b128.
__device__ __forceinline__ bfrag fr8(const u16* base, int row, int gi) {
  return *(const bfrag*)&base[row * 64 + ((gi ^ (row & 7)) * 8)];
}
__device__ __forceinline__ bfrag fr4(const u16* base, int row, int gi) {
  return *(const bfrag*)&base[row * 32 + ((gi ^ (row & 3)) * 8)];
}

// ------- kernel 1: fused weights->bf16 + BN-stat/counter zero + x transpose -------
// grid (64,16,5): z<4 -> xpose batch z; z==4 -> weight convert (1024 blocks).
__global__ void k_misc(const float* __restrict__ x, const float* __restrict__ gw,
                       const float* __restrict__ tw, const float* __restrict__ pw,
                       const float* __restrict__ ww, u16* __restrict__ xT,
                       u16* __restrict__ Wcat, u16* __restrict__ Ww,
                       float* __restrict__ stats) {
  int b = blockIdx.z;
  if (b == 4) {  // weight convert path
    int i = (blockIdx.y * 64 + blockIdx.x) * 256 + threadIdx.x;
    if (i < CIn * Cn) {
      Wcat[i]                = f2bf(tw[i] * SCF);  // theta (Q), pre-scaled
      Wcat[CIn * Cn + i]     = f2bf(pw[i]);        // phi   (K)
      Wcat[2 * CIn * Cn + i] = f2bf(gw[i]);        // g     (V)
      Ww[i]                  = f2bf(ww[i]);
    }
    if (i < 2 * Cn + 512) stats[i] = 0.f;  // BN sums + attn arrival counters
    return;
  }
  __shared__ float tile[32][33];
  int l0 = blockIdx.x * 32, c0 = blockIdx.y * 32;
  int tx = threadIdx.x & 31, ty = threadIdx.x >> 5;
  const float* xb = x + (size_t)b * Cn * Ln;
  for (int k = 0; k < 4; k++)
    tile[ty + k * 8][tx] = xb[(size_t)(c0 + ty + k * 8) * Ln + l0 + tx];
  __syncthreads();
  u16* xtb = xT + (size_t)b * Ln * Cn;
  int cc = (threadIdx.x & 15) * 2, r0 = threadIdx.x >> 4;
  for (int k = 0; k < 2; k++) {
    int ll = r0 + k * 16;
    u32 pk = pkbf(tile[cc][ll], tile[cc + 1][ll]);
    *(u32*)&xtb[(size_t)(l0 + ll) * Cn + c0 + cc] = pk;
  }
}

// ------------- GEMM cores: C[M,128] = A[M,K] * Bt[128,K]^T -------------
__device__ __forceinline__ void stage128x32(const u16* g, int K, int k0, u16* lds,
                                            int w, int l) {
  int gsw = ((l & 3) ^ ((l >> 3) & 3)) * 8;
  for (int jj = 0; jj < 2; jj++) {
    int j = w * 2 + jj;
    const u16* ga = g + (size_t)(j * 16 + (l >> 2)) * K + k0 + gsw;
    async16(ga, (char*)lds + j * 1024 + l * 16);
  }
}

__device__ __forceinline__ void gemm_core(const u16* A, const u16* Bt, int K,
                                          u16* As, u16* Bs, facc acc[4][4],
                                          int w, int l) {
  int quad = l >> 4, lo = l & 15;
  int mw = (w >> 1) * 64, nw = (w & 1) * 64;
  int rsw = (lo >> 1) & 3;
  for (int k0 = 0; k0 < K; k0 += 32) {
    stage128x32(A, K, k0, As, w, l);
    stage128x32(Bt, K, k0, Bs, w, l);
    __syncthreads();
    bfrag af[4], bfv[4];
    for (int mi = 0; mi < 4; mi++)
      af[mi] = *(const bfrag*)&As[(mw + mi * 16 + lo) * 32 + ((quad ^ rsw) * 8)];
    for (int ni = 0; ni < 4; ni++)
      bfv[ni] = *(const bfrag*)&Bs[(nw + ni * 16 + lo) * 32 + ((quad ^ rsw) * 8)];
    for (int mi = 0; mi < 4; mi++)
      for (int ni = 0; ni < 4; ni++)
        acc[mi][ni] = mfma16(af[mi], bfv[ni], acc[mi][ni]);
    __syncthreads();
  }
}

// 64xK * Bt[128,K]^T variant (for k_wgemm)
__device__ __forceinline__ void gemm_core64(const u16* A, const u16* Bt, int K,
                                            u16* As, u16* Bs, facc acc[2][4],
                                            int w, int l) {
  int quad = l >> 4, lo = l & 15;
  int mw = (w >> 1) * 32, nw = (w & 1) * 64;
  int rsw = (lo >> 1) & 3;
  int gsw = ((l & 3) ^ ((l >> 3) & 3)) * 8;
  for (int k0 = 0; k0 < K; k0 += 32) {
    async16(A + (size_t)(w * 16 + (l >> 2)) * K + k0 + gsw, (char*)As + w * 1024 + l * 16);
    stage128x32(Bt, K, k0, Bs, w, l);
    __syncthreads();
    bfrag af[2], bfv[4];
    for (int mi = 0; mi < 2; mi++)
      af[mi] = *(const bfrag*)&As[(mw + mi * 16 + lo) * 32 + ((quad ^ rsw) * 8)];
    for (int ni = 0; ni < 4; ni++)
      bfv[ni] = *(const bfrag*)&Bs[(nw + ni * 16 + lo) * 32 + ((quad ^ rsw) * 8)];
    for (int mi = 0; mi < 2; mi++)
      for (int ni = 0; ni < 4; ni++)
        acc[mi][ni] = mfma16(af[mi], bfv[ni], acc[mi][ni]);
    __syncthreads();
  }
}

// ---------------- kernel 2: fused projection GEMM + head-split epilogue ----------------
__global__ __launch_bounds__(256) void k_proj(
    const u16* __restrict__ Wcat, const u16* __restrict__ xT,
    const float* __restrict__ tb, const float* __restrict__ pb,
    const float* __restrict__ gb, u16* __restrict__ Q, u16* __restrict__ Kb,
    u16* __restrict__ Vt) {
  __shared__ __align__(16) u16 As[128 * 32];
  __shared__ __align__(16) u16 Bs[128 * 32];
  int w = threadIdx.x >> 6, l = threadIdx.x & 63;
  int quad = l >> 4, lo = l & 15;
  int m0 = blockIdx.y * 128, n0 = blockIdx.x * 128, b = blockIdx.z;
  facc acc[4][4] = {};
  gemm_core(Wcat + (size_t)m0 * Cn, xT + ((size_t)b * Ln + n0) * Cn, Cn, As, Bs, acc, w, l);
  int mw = (w >> 1) * 64, nw = (w & 1) * 64;
  int chunk = m0 >> 9;
  for (int mi = 0; mi < 4; mi++) {
    int mo = (m0 + mw + mi * 16) & 511;
    int hh = mo >> 6;
    int db = (mo & 63) + quad * 4;
    int bi = mo + quad * 4;
    if (chunk < 2) {  // theta -> Q (bias pre-scaled), phi -> Kb; layout [B,H,L,D]
      const float* bias = (chunk == 0) ? tb : pb;
      float bs = (chunk == 0) ? SCF : 1.0f;
      u16* dst0 = ((chunk == 0) ? Q : Kb) + (size_t)(b * Hn + hh) * Ln * 64 + db;
      float b0 = bias[bi] * bs, b1 = bias[bi + 1] * bs;
      float b2 = bias[bi + 2] * bs, b3 = bias[bi + 3] * bs;
      for (int ni = 0; ni < 4; ni++) {
        int lcol = n0 + nw + ni * 16 + lo;
        facc a = acc[mi][ni];
        uint2 pk;
        pk.x = pkbf(a[0] + b0, a[1] + b1);
        pk.y = pkbf(a[2] + b2, a[3] + b3);
        *(uint2*)(dst0 + (size_t)lcol * 64) = pk;
      }
    } else {          // g -> Vt, layout [B,H,D,L]
      for (int ni = 0; ni < 4; ni++) {
        int lcol = n0 + nw + ni * 16 + lo;
        facc a = acc[mi][ni];
        for (int r = 0; r < 4; r++)
          Vt[((size_t)(b * Hn + hh) * Dn + db + r) * Ln + lcol] = f2bf_fast(a[r] + gb[bi + r]);
      }
    }
  }
}

// ---------------- kernel 3: flash attention + fused split-K combine ----------------
// Fixed-max softmax (scores |s|~1 in log2 domain): partials exactly linear.
// K-tile 32, dbuf; LDS 32KB -> 4 blocks/CU resident (grid = 4/CU exactly).
// Second-arriving block of each split pair combines via device-scope counter.
__global__ __launch_bounds__(256, 4) void k_attn(
    const u16* __restrict__ Q, const u16* __restrict__ Kb,
    const u16* __restrict__ Vt, u16* __restrict__ Opart,
    float* __restrict__ lpart, int* __restrict__ cnt, u16* __restrict__ yT) {
  // Ks: 2 x [32 kpos][64 d] (8KB) | Vs: 2 x [64 d][32 kpos] (8KB) | QPs 16KB
  __shared__ __align__(16) u16 lds[16384];
  __shared__ int sOld;
  u16* Ks = lds;
  u16* Vs = lds + 4096;
  u16* QPs = lds + 8192;  // Q tile [128 q][64 d]; later per-wave P strips (rows w*32..)
  int w = threadIdx.x >> 6, l = threadIdx.x & 63;
  int quad = l >> 4, lo = l & 15;
  int q0 = blockIdx.x * 128, h = blockIdx.y >> 1, split = blockIdx.y & 1, b = blockIdx.z;
  size_t bh = (size_t)b * Hn + h;
  const u16* Qg = Q + bh * Ln * 64;
  const u16* Kg = Kb + bh * Ln * 64 + (size_t)split * 1024 * 64;  // split's K half
  const u16* Vg = Vt + bh * (size_t)Dn * Ln + split * 1024;       // split's V cols

  int rin = l >> 3;
  int gg = ((l & 7) ^ rin) * 8;                    // 128B-row source swizzle
  int ggv = ((l & 3) ^ ((l >> 2) & 3)) * 8;        // 64B-row source swizzle (V)

  for (int jj = 0; jj < 4; jj++) {  // wave stages its OWN 32 Q rows (16KB tile)
    int j = w * 4 + jj;
    async16(Qg + (size_t)(q0 + j * 8 + rin) * 64 + gg, (char*)QPs + j * 1024 + l * 16);
  }
  // tile 0 -> buf 0: K chunk w (8 rows x 128B), V chunk w (16 rows x 64B)
  async16(Kg + (size_t)(w * 8 + rin) * 64 + gg, (char*)Ks + w * 1024 + l * 16);
  async16(Vg + (size_t)(w * 16 + (l >> 2)) * Ln + ggv, (char*)Vs + w * 1024 + l * 16);
  __syncthreads();
  bfrag qf[2][2];  // wave-private rows, hoisted before P overwrites QPs
  for (int s = 0; s < 2; s++)
    for (int c = 0; c < 2; c++)
      qf[s][c] = fr8(QPs, w * 32 + s * 16 + lo, c * 4 + quad);

  facc o[2][4] = {};  // O^T[d = mi*16+quad*4+r][q = qset*16+lo]
  float l_i[2] = {0.f, 0.f};

  for (int t = 0; t < 32; t++) {  // 32 tiles of 32 kpos = this split's 1024
    const u16* Kc = Ks + (t & 1) * 2048;
    const u16* Vc = Vs + (t & 1) * 2048;
    if (t < 31) {  // prefetch next tile into other buffer
      int nb = (~t & 1) * 2048;
      int kbase = (t + 1) * 32;
      async16(Kg + (size_t)(kbase + w * 8 + rin) * 64 + gg,
              (char*)(Ks + nb) + w * 1024 + l * 16);
      async16(Vg + (size_t)(w * 16 + (l >> 2)) * Ln + kbase + ggv,
              (char*)(Vs + nb) + w * 1024 + l * 16);
    }
    for (int ni = 0; ni < 2; ni++) {
      bfrag kf0 = fr8(Kc, ni * 16 + lo, quad);
      bfrag kf1 = fr8(Kc, ni * 16 + lo, 4 + quad);
      for (int s = 0; s < 2; s++) {
        facc z = {};
        facc stv = mfma16(kf1, qf[s][1], mfma16(kf0, qf[s][0], z));
        float p0 = __builtin_amdgcn_exp2f(stv[0]);
        float p1 = __builtin_amdgcn_exp2f(stv[1]);
        float p2 = __builtin_amdgcn_exp2f(stv[2]);
        float p3 = __builtin_amdgcn_exp2f(stv[3]);
        l_i[s] += (p0 + p1) + (p2 + p3);
        int row = w * 32 + s * 16 + lo;
        uint2 pk;
        pk.x = pkbf(p0, p1);
        pk.y = pkbf(p2, p3);
        int gi = ni * 2 + (quad >> 1);  // kpos granule (0..3), sub (quad&1)*4
        *(uint2*)&QPs[row * 64 + ((gi ^ (row & 7)) * 8) + (quad & 1) * 4] = pk;
      }
    }
    bfrag pb2[2];  // B-operand: kpos k-dim (32), wave-private strip
    for (int s = 0; s < 2; s++)
      pb2[s] = fr8(QPs, w * 32 + s * 16 + lo, quad);
    for (int mi = 0; mi < 4; mi++) {
      bfrag vf = fr4(Vc, mi * 16 + lo, quad);
      for (int s = 0; s < 2; s++)
        o[s][mi] = mfma16(vf, pb2[s], o[s][mi]);
    }
    __syncthreads();  // prefetch drained + buffers/P-strip safe to reuse
  }

  // ---- epilogue: store un-normalized partial, then second arriver combines ----
  int sb = split * 32 + (int)bh;
  float lt[2];
  for (int s = 0; s < 2; s++) {
    float v = l_i[s];
    v += __shfl_xor(v, 16);
    v += __shfl_xor(v, 32);
    lt[s] = v;
    int q = q0 + w * 32 + s * 16 + lo;
    u16* dst = Opart + ((size_t)sb * Ln + q) * 64;
    for (int mi = 0; mi < 4; mi++) {
      uint2 pk;
      pk.x = pkbf(o[s][mi][0], o[s][mi][1]);
      pk.y = pkbf(o[s][mi][2], o[s][mi][3]);
      *(uint2*)(dst + mi * 16 + quad * 4) = pk;
    }
    if (quad == 0) lpart[(size_t)sb * Ln + q] = lt[s];
  }
  __threadfence();  // release partials (device scope)
  __syncthreads();
  if (threadIdx.x == 0)
    sOld = atomicAdd(cnt + ((int)bh * 16 + blockIdx.x), 1);
  __syncthreads();
  if (sOld == 0) return;  // first arriver done; second combines
  __threadfence();        // acquire other block's stores
  int sbo = (1 - split) * 32 + (int)bh;
  for (int s = 0; s < 2; s++) {
    int q = q0 + w * 32 + s * 16 + lo;
    const u16* osrc = Opart + ((size_t)sbo * Ln + q) * 64;
    float inv = 1.0f / (lt[s] + lpart[(size_t)sbo * Ln + q]);
    u16* dst = yT + ((size_t)b * Ln + q) * CIn + h * 64;
    for (int mi = 0; mi < 4; mi++) {
      uint2 ov = *(const uint2*)(osrc + mi * 16 + quad * 4);
      uint2 pk;
      pk.x = pkbf((o[s][mi][0] + bflo(ov.x)) * inv, (o[s][mi][1] + bfhi(ov.x)) * inv);
      pk.y = pkbf((o[s][mi][2] + bflo(ov.y)) * inv, (o[s][mi][3] + bfhi(ov.y)) * inv);
      *(uint2*)(dst + mi * 16 + quad * 4) = pk;
    }
  }
}

// ---------------- kernel 4: W GEMM (64x128 tiles) + BN statistics ----------------
__global__ __launch_bounds__(256) void k_wgemm(
    const u16* __restrict__ Ww, const u16* __restrict__ yT,
    const float* __restrict__ wb, u16* __restrict__ wy,
    float* __restrict__ stats) {
  __shared__ __align__(16) u16 As[64 * 32];
  __shared__ __align__(16) u16 Bs[128 * 32];
  int w = threadIdx.x >> 6, l = threadIdx.x & 63;
  int quad = l >> 4, lo = l & 15;
  int m0 = blockIdx.y * 64, n0 = blockIdx.x * 128, b = blockIdx.z;
  facc acc[2][4] = {};
  gemm_core64(Ww + (size_t)m0 * CIn, yT + ((size_t)b * Ln + n0) * CIn, CIn, As, Bs, acc, w, l);
  int mw = (w >> 1) * 32, nw = (w & 1) * 64;
  for (int mi = 0; mi < 2; mi++) {
    int cb = m0 + mw + mi * 16 + quad * 4;
    for (int r = 0; r < 4; r++) {
      float bias = wb[cb + r];
      float s = 0.f, q = 0.f;
      for (int ni = 0; ni < 4; ni++) {
        float v = acc[mi][ni][r] + bias;
        wy[((size_t)b * Cn + cb + r) * Ln + n0 + nw + ni * 16 + lo] = f2bf_fast(v);
        s += v; q += v * v;  // stats from fp32 pre-round values
      }
      for (int mask = 1; mask < 16; mask <<= 1) {
        s += __shfl_xor(s, mask);
        q += __shfl_xor(q, mask);
      }
      if (lo == 0) {
        atomicAdd(&stats[cb + r], s);
        atomicAdd(&stats[Cn + cb + r], q);
      }
    }
  }
}

// ---------------- kernel 5: BN apply (bf16 in, f32 out) ----------------
__global__ void k_bn(const u16* __restrict__ wy, const float* __restrict__ stats,
                     const float* __restrict__ gam, const float* __restrict__ bet,
                     float* __restrict__ out) {
  int i = blockIdx.x * 256 + threadIdx.x;
  size_t idx = (size_t)i * 8;
  int c = (int)((idx >> 11) & (Cn - 1));  // [B,C,L], L=2^11
  const float invN = 1.f / (Bn * Ln);
  float mean = stats[c] * invN;
  float var = stats[Cn + c] * invN - mean * mean;
  float scl = gam[c] * rsqrtf(var + 1e-5f);
  float sh = bet[c] - mean * scl;
  uint4 v = *(const uint4*)(wy + idx);
  float4 o0, o1;
  o0.x = bflo(v.x) * scl + sh; o0.y = bfhi(v.x) * scl + sh;
  o0.z = bflo(v.y) * scl + sh; o0.w = bfhi(v.y) * scl + sh;
  o1.x = bflo(v.z) * scl + sh; o1.y = bfhi(v.z) * scl + sh;
  o1.z = bflo(v.w) * scl + sh; o1.w = bfhi(v.w) * scl + sh;
  *(float4*)(out + idx) = o0;
  *(float4*)(out + idx + 4) = o1;
}

extern "C" void kernel_launch(void* const* d_in, const int* in_sizes, int n_in,
                              void* d_out, int out_size, void* d_ws, size_t ws_size,
                              hipStream_t stream) {
  const float* x   = (const float*)d_in[0];
  const float* g_w = (const float*)d_in[1];
  const float* g_b = (const float*)d_in[2];
  const float* t_w = (const float*)d_in[3];
  const float* t_b = (const float*)d_in[4];
  const float* p_w = (const float*)d_in[5];
  const float* p_b = (const float*)d_in[6];
  const float* w_w = (const float*)d_in[7];
  const float* w_b = (const float*)d_in[8];
  const float* gam = (const float*)d_in[9];
  const float* bet = (const float*)d_in[10];
  float* out = (float*)d_out;

  char* ws = (char*)d_ws;
  size_t off = 0;
  auto alloc = [&](size_t bytes) {
    char* p = ws + off; off += (bytes + 255) & ~(size_t)255; return p;
  };
  u16*  xT   = (u16*)alloc((size_t)Bn * Ln * Cn * 2);      // x^T bf16
  u16*  Wcat = (u16*)alloc((size_t)COn * Cn * 2);          // [theta;phi;g] bf16
  u16*  Ww   = (u16*)alloc((size_t)Cn * CIn * 2);          // w_w bf16
  u16*  Qb   = (u16*)alloc((size_t)Bn * Hn * Ln * Dn * 2); // theta  [B,H,L,D]
  u16*  Kb   = (u16*)alloc((size_t)Bn * Hn * Ln * Dn * 2); // phi    [B,H,L,D]
  u16*  Vt   = (u16*)alloc((size_t)Bn * Hn * Dn * Ln * 2); // g      [B,H,D,L]
  u16*  yT   = (u16*)alloc((size_t)Bn * Ln * CIn * 2);     // attn out [B,L,CI]
  // Opart (attn partials, dead after attn) aliases wy (written by k_wgemm after)
  size_t opart_bytes = (size_t)2 * 32 * Ln * 64 * 2;       // 16.8 MB
  u16*  Opart = (u16*)alloc(opart_bytes);                  // also wy
  u16*  wy    = Opart;
  float* lpart = (float*)alloc((size_t)2 * 32 * Ln * 4);   // split l sums
  float* st  = (float*)alloc((2 * Cn + 512) * 4);          // BN sums + counters
  int*  cnt  = (int*)(st + 2 * Cn);
  if (ws_size < off) return;  // ~55 MB required

  k_misc<<<dim3(64, 16, 5), 256, 0, stream>>>(x, g_w, t_w, p_w, w_w, xT, Wcat, Ww, st);
  k_proj<<<dim3(16, 12, 4), 256, 0, stream>>>(Wcat, xT, t_b, p_b, g_b, Qb, Kb, Vt);
  k_attn<<<dim3(16, 16, 4), 256, 0, stream>>>(Qb, Kb, Vt, Opart, lpart, cnt, yT);
  k_wgemm<<<dim3(16, 8, 4), 256, 0, stream>>>(Ww, yT, w_b, wy, st);
  k_bn<<<dim3(2048), 256, 0, stream>>>(wy, st, gam, bet, out);
}

// Round 6
// 196.136 us; speedup vs baseline: 1.9520x; 1.9520x over previous
//
#include <hip/hip_runtime.h>

// Problem constants (match reference)
constexpr int Bn = 4, Cn = 512, Ln = 2048, CIn = 512, Hn = 8, Dn = 64;
constexpr int COn = 3 * CIn;  // 1536 stacked output channels: [theta; phi; g]

typedef unsigned short u16;
typedef unsigned int u32;
typedef __attribute__((ext_vector_type(8))) short bfrag;  // 8 x bf16 (4 VGPRs)
typedef __attribute__((ext_vector_type(4))) float facc;   // 4 x f32 acc

// 1/sqrt(D) * log2(e): folded into theta weights/bias so QK^T lands in log2 domain
#define SCF 0.180336879f

__device__ __forceinline__ facc mfma16(bfrag a, bfrag b, facc c) {
  return __builtin_amdgcn_mfma_f32_16x16x32_bf16(a, b, c, 0, 0, 0);
}

__device__ __forceinline__ void async16(const void* g, void* l) {
  __builtin_amdgcn_global_load_lds((const __attribute__((address_space(1))) void*)g,
                                   (__attribute__((address_space(3))) void*)l, 16, 0, 0);
}

__device__ __forceinline__ u16 f2bf(float x) {  // RNE float->bf16
  union { float f; u32 u; } v; v.f = x;
  u32 r = v.u + 0x7FFFu + ((v.u >> 16) & 1u);
  return (u16)(r >> 16);
}

__device__ __forceinline__ u16 f2bf_fast(float x) {  // round-half-up, 2 ops
  union { float f; u32 u; } v; v.f = x;
  return (u16)((v.u + 0x8000u) >> 16);
}

// pack 2 floats -> bf16x2 in one u32: 2 round-adds + 1 v_perm
__device__ __forceinline__ u32 pkbf(float lof, float hif) {
  union { float f; u32 u; } a, b; a.f = lof; b.f = hif;
  return __builtin_amdgcn_perm(b.u + 0x8000u, a.u + 0x8000u, 0x07060302u);
}

__device__ __forceinline__ float bflo(u32 u) { return __uint_as_float(u << 16); }
__device__ __forceinline__ float bfhi(u32 u) { return __uint_as_float(u & 0xFFFF0000u); }

// Swizzled frag read for row-stride-64-u16 (128B) tiles: granule gi (16B units)
// of row `row` lives at position gi ^ (row&7). Conflict-free b128 reads.
__device__ __forceinline__ bfrag fr8(const u16* base, int row, int gi) {
  return *(const bfrag*)&base[row * 64 + ((gi ^ (row & 7)) * 8)];
}

// ------- kernel 1: fused weights->bf16 + BN-stat zero + x transpose -------
// grid (64,16,5): z<4 -> xpose batch z; z==4 -> weight convert (1024 blocks).
__global__ void k_misc(const float* __restrict__ x, const float* __restrict__ gw,
                       const float* __restrict__ tw, const float* __restrict__ pw,
                       const float* __restrict__ ww, u16* __restrict__ xT,
                       u16* __restrict__ Wcat, u16* __restrict__ Ww,
                       float* __restrict__ stats) {
  int b = blockIdx.z;
  if (b == 4) {  // weight convert path
    int i = (blockIdx.y * 64 + blockIdx.x) * 256 + threadIdx.x;
    if (i < CIn * Cn) {
      Wcat[i]                = f2bf(tw[i] * SCF);  // theta (Q), pre-scaled
      Wcat[CIn * Cn + i]     = f2bf(pw[i]);        // phi   (K)
      Wcat[2 * CIn * Cn + i] = f2bf(gw[i]);        // g     (V)
      Ww[i]                  = f2bf(ww[i]);
    }
    if (i < 2 * Cn) stats[i] = 0.f;  // d_ws is poisoned each launch
    return;
  }
  __shared__ float tile[32][33];
  int l0 = blockIdx.x * 32, c0 = blockIdx.y * 32;
  int tx = threadIdx.x & 31, ty = threadIdx.x >> 5;
  const float* xb = x + (size_t)b * Cn * Ln;
  for (int k = 0; k < 4; k++)
    tile[ty + k * 8][tx] = xb[(size_t)(c0 + ty + k * 8) * Ln + l0 + tx];
  __syncthreads();
  u16* xtb = xT + (size_t)b * Ln * Cn;
  int cc = (threadIdx.x & 15) * 2, r0 = threadIdx.x >> 4;
  for (int k = 0; k < 2; k++) {
    int ll = r0 + k * 16;
    u32 pk = pkbf(tile[cc][ll], tile[cc + 1][ll]);
    *(u32*)&xtb[(size_t)(l0 + ll) * Cn + c0 + cc] = pk;
  }
}

// ------------- GEMM core: C[128,128] = A[128,K] * Bt[128,K]^T -------------
__device__ __forceinline__ void stage128x32(const u16* g, int K, int k0, u16* lds,
                                            int w, int l) {
  int gsw = ((l & 3) ^ ((l >> 3) & 3)) * 8;
  for (int jj = 0; jj < 2; jj++) {
    int j = w * 2 + jj;
    const u16* ga = g + (size_t)(j * 16 + (l >> 2)) * K + k0 + gsw;
    async16(ga, (char*)lds + j * 1024 + l * 16);
  }
}

// SWAP=1 computes C^T tiles (A-operand = Bt rows) for packed transposed stores.
template <int SWAP>
__device__ __forceinline__ void gemm_core(const u16* A, const u16* Bt, int K,
                                          u16* As, u16* Bs, facc acc[4][4],
                                          int w, int l) {
  int quad = l >> 4, lo = l & 15;
  int mw = (w >> 1) * 64, nw = (w & 1) * 64;
  int rsw = (lo >> 1) & 3;
  for (int k0 = 0; k0 < K; k0 += 32) {
    stage128x32(A, K, k0, As, w, l);
    stage128x32(Bt, K, k0, Bs, w, l);
    __syncthreads();
    bfrag af[4], bfv[4];
    for (int mi = 0; mi < 4; mi++)
      af[mi] = *(const bfrag*)&As[(mw + mi * 16 + lo) * 32 + ((quad ^ rsw) * 8)];
    for (int ni = 0; ni < 4; ni++)
      bfv[ni] = *(const bfrag*)&Bs[(nw + ni * 16 + lo) * 32 + ((quad ^ rsw) * 8)];
    for (int mi = 0; mi < 4; mi++)
      for (int ni = 0; ni < 4; ni++)
        acc[mi][ni] = SWAP ? mfma16(bfv[ni], af[mi], acc[mi][ni])
                           : mfma16(af[mi], bfv[ni], acc[mi][ni]);
    __syncthreads();
  }
}

// ---------------- kernel 2: fused projection GEMM + head-split epilogue ----------------
// Q/K blocks: C rows = channels, cols = l -> [B,H,L,D] packed-d stores.
// V blocks: operand-swapped MFMA -> lane holds 4 consecutive l for one channel
// -> [B,H,D,L] packed-l stores (was 64 scalar 2B scatters per lane).
__global__ __launch_bounds__(256) void k_proj(
    const u16* __restrict__ Wcat, const u16* __restrict__ xT,
    const float* __restrict__ tb, const float* __restrict__ pb,
    const float* __restrict__ gb, u16* __restrict__ Q, u16* __restrict__ Kb,
    u16* __restrict__ Vt) {
  __shared__ __align__(16) u16 As[128 * 32];
  __shared__ __align__(16) u16 Bs[128 * 32];
  int w = threadIdx.x >> 6, l = threadIdx.x & 63;
  int quad = l >> 4, lo = l & 15;
  int m0 = blockIdx.y * 128, n0 = blockIdx.x * 128, b = blockIdx.z;
  int chunk = m0 >> 9;  // 128-tiles never straddle 512-row chunks
  facc acc[4][4] = {};
  const u16* Ap = Wcat + (size_t)m0 * Cn;
  const u16* Bp = xT + ((size_t)b * Ln + n0) * Cn;
  int mw = (w >> 1) * 64, nw = (w & 1) * 64;
  if (chunk < 2) {
    gemm_core<0>(Ap, Bp, Cn, As, Bs, acc, w, l);
    const float* bias = (chunk == 0) ? tb : pb;
    float bs = (chunk == 0) ? SCF : 1.0f;
    for (int mi = 0; mi < 4; mi++) {
      int mo = (m0 + mw + mi * 16) & 511;
      int hh = mo >> 6;
      int db = (mo & 63) + quad * 4;
      int bi = mo + quad * 4;
      u16* dst0 = ((chunk == 0) ? Q : Kb) + (size_t)(b * Hn + hh) * Ln * 64 + db;
      float b0 = bias[bi] * bs, b1 = bias[bi + 1] * bs;
      float b2 = bias[bi + 2] * bs, b3 = bias[bi + 3] * bs;
      for (int ni = 0; ni < 4; ni++) {
        int lcol = n0 + nw + ni * 16 + lo;
        facc a = acc[mi][ni];
        uint2 pk;
        pk.x = pkbf(a[0] + b0, a[1] + b1);
        pk.y = pkbf(a[2] + b2, a[3] + b3);
        *(uint2*)(dst0 + (size_t)lcol * 64) = pk;
      }
    }
  } else {  // g -> Vt [B,H,D,L], transposed accumulation
    gemm_core<1>(Ap, Bp, Cn, As, Bs, acc, w, l);
    for (int mi = 0; mi < 4; mi++) {
      int ch = (m0 + mw + mi * 16 + lo) & 511;  // channel per lane
      int hh = ch >> 6, d = ch & 63;
      float bias = gb[ch];
      u16* dst0 = Vt + ((size_t)(b * Hn + hh) * Dn + d) * Ln;
      for (int ni = 0; ni < 4; ni++) {
        int l0 = n0 + nw + ni * 16 + quad * 4;  // 4 consecutive l in acc regs
        facc a = acc[mi][ni];
        uint2 pk;
        pk.x = pkbf(a[0] + bias, a[1] + bias);
        pk.y = pkbf(a[2] + bias, a[3] + bias);
        *(uint2*)(dst0 + l0) = pk;
      }
    }
  }
}

// ---------------- kernel 3: flash attention, fixed-max softmax, split-K x2 ----------------
// R4-proven structure: K-tile 64 dbuf, LDS 48KB, 3 blocks/CU, no fences.
// Fixed-max (scores |s|~1 in log2 domain, overflow needs |s|>126): partials
// exactly linear: O = O1+O2, l = l1+l2. Partials un-normalized bf16.
__global__ __launch_bounds__(256, 2) void k_attn(
    const u16* __restrict__ Q, const u16* __restrict__ Kb,
    const u16* __restrict__ Vt, u16* __restrict__ Opart,
    float* __restrict__ lpart) {
  __shared__ __align__(16) u16 lds[24576];  // Ks[2][4096] | Vs[2][4096] | QPs[8192]
  u16* Ks = lds;
  u16* Vs = lds + 8192;
  u16* QPs = lds + 16384;
  int w = threadIdx.x >> 6, l = threadIdx.x & 63;
  int quad = l >> 4, lo = l & 15;
  int q0 = blockIdx.x * 128, h = blockIdx.y >> 1, split = blockIdx.y & 1, b = blockIdx.z;
  size_t bh = (size_t)b * Hn + h;
  const u16* Qg = Q + bh * Ln * 64;
  const u16* Kg = Kb + bh * Ln * 64 + (size_t)split * 1024 * 64;  // split's K half
  const u16* Vg = Vt + bh * (size_t)Dn * Ln + split * 1024;       // split's V cols

  int rin = l >> 3;
  int gg = ((l & 7) ^ rin) * 8;

  for (int jj = 0; jj < 4; jj++) {  // wave stages its OWN 32 Q rows
    int j = w * 4 + jj;
    async16(Qg + (size_t)(q0 + j * 8 + rin) * 64 + gg, (char*)QPs + j * 1024 + l * 16);
  }
  for (int jj = 0; jj < 2; jj++) {  // K/V tile 0 -> buf 0
    int j = w * 2 + jj;
    async16(Kg + (size_t)(j * 8 + rin) * 64 + gg, (char*)Ks + j * 1024 + l * 16);
    async16(Vg + (size_t)(j * 8 + rin) * Ln + gg, (char*)Vs + j * 1024 + l * 16);
  }
  __syncthreads();
  bfrag qf[2][2];  // wave-private rows, hoisted before P overwrites QPs
  for (int s = 0; s < 2; s++)
    for (int c = 0; c < 2; c++)
      qf[s][c] = fr8(QPs, w * 32 + s * 16 + lo, c * 4 + quad);

  facc o[2][4] = {};  // O^T[d = mi*16+quad*4+r][q = qset*16+lo]
  float l_i[2] = {0.f, 0.f};

  for (int t = 0; t < 16; t++) {  // 16 tiles of 64 = this split's 1024 kpos
    const u16* Kc = Ks + (t & 1) * 4096;
    const u16* Vc = Vs + (t & 1) * 4096;
    if (t < 15) {  // prefetch next tile into other buffer
      int nb = (~t & 1) * 4096;
      int kbase = (t + 1) * 64;
      for (int jj = 0; jj < 2; jj++) {
        int j = w * 2 + jj;
        async16(Kg + (size_t)(kbase + j * 8 + rin) * 64 + gg,
                (char*)(Ks + nb) + j * 1024 + l * 16);
        async16(Vg + (size_t)(j * 8 + rin) * Ln + kbase + gg,
                (char*)(Vs + nb) + j * 1024 + l * 16);
      }
    }
    for (int ni = 0; ni < 4; ni++) {
      bfrag kf0 = fr8(Kc, ni * 16 + lo, quad);
      bfrag kf1 = fr8(Kc, ni * 16 + lo, 4 + quad);
      for (int s = 0; s < 2; s++) {
        facc z = {};
        facc stv = mfma16(kf1, qf[s][1], mfma16(kf0, qf[s][0], z));
        float p0 = __builtin_amdgcn_exp2f(stv[0]);
        float p1 = __builtin_amdgcn_exp2f(stv[1]);
        float p2 = __builtin_amdgcn_exp2f(stv[2]);
        float p3 = __builtin_amdgcn_exp2f(stv[3]);
        l_i[s] += (p0 + p1) + (p2 + p3);
        int row = w * 32 + s * 16 + lo;
        uint2 pk;
        pk.x = pkbf(p0, p1);
        pk.y = pkbf(p2, p3);
        int gi = ni * 2 + (quad >> 1);
        *(uint2*)&QPs[row * 64 + ((gi ^ (row & 7)) * 8) + (quad & 1) * 4] = pk;
      }
    }
    bfrag pb2[2][2];
    for (int s = 0; s < 2; s++)
      for (int c = 0; c < 2; c++)
        pb2[s][c] = fr8(QPs, w * 32 + s * 16 + lo, c * 4 + quad);
    for (int mi = 0; mi < 4; mi++) {
      bfrag vf0 = fr8(Vc, mi * 16 + lo, quad);
      bfrag vf1 = fr8(Vc, mi * 16 + lo, 4 + quad);
      for (int s = 0; s < 2; s++)
        o[s][mi] = mfma16(vf1, pb2[s][1], mfma16(vf0, pb2[s][0], o[s][mi]));
    }
    __syncthreads();
  }
  // epilogue: un-normalized O partial (bf16) + l partial (f32)
  int sb = split * 32 + (int)bh;  // [split][bh]
  for (int s = 0; s < 2; s++) {
    float lt = l_i[s];
    lt += __shfl_xor(lt, 16);
    lt += __shfl_xor(lt, 32);
    int q = q0 + w * 32 + s * 16 + lo;
    u16* dst = Opart + ((size_t)sb * Ln + q) * 64;
    for (int mi = 0; mi < 4; mi++) {
      uint2 pk;
      pk.x = pkbf(o[s][mi][0], o[s][mi][1]);
      pk.y = pkbf(o[s][mi][2], o[s][mi][3]);
      *(uint2*)(dst + mi * 16 + quad * 4) = pk;
    }
    if (quad == 0) lpart[(size_t)sb * Ln + q] = lt;
  }
}

// ---------------- kernel 4: W GEMM (64x128) + fused split-K combine + BN stats ----------
// B-tile built on the fly from Opart/lpart (combine+normalize) via swizzled
// ds_write_b128 matching stage128x32's slot convention. Deletes k_comb + yT.
__global__ __launch_bounds__(256) void k_wgemm(
    const u16* __restrict__ Ww, const u16* __restrict__ Opart,
    const float* __restrict__ lpart, const float* __restrict__ wb,
    u16* __restrict__ wy, float* __restrict__ stats) {
  __shared__ __align__(16) u16 As[64 * 32];
  __shared__ __align__(16) u16 Bs[128 * 32];
  int tid = threadIdx.x;
  int w = tid >> 6, l = tid & 63;
  int quad = l >> 4, lo = l & 15;
  int m0 = blockIdx.y * 64, n0 = blockIdx.x * 128, b = blockIdx.z;
  const u16* A = Ww + (size_t)m0 * CIn;
  facc acc[2][4] = {};
  int gsw = ((l & 3) ^ ((l >> 3) & 3)) * 8;
  int rsw = (lo >> 1) & 3;
  int mw = (w >> 1) * 32, nw = (w & 1) * 64;
  int row = tid >> 1;        // B-combine: 2 lanes per l-row
  int rg = n0 + row;
  int half = tid & 1;        // which 16-d half of the 32-ci k-slice
  int ssw = (row >> 1) & 3;  // slot swizzle term for this row
  for (int k0 = 0; k0 < CIn; k0 += 32) {
    async16(A + (size_t)(w * 16 + (l >> 2)) * CIn + k0 + gsw,
            (char*)As + w * 1024 + l * 16);
    int h = k0 >> 6;
    int sb0 = b * 8 + h;
    const u16* p1 = Opart + ((size_t)sb0 * Ln + rg) * 64 + (k0 & 63) + half * 16;
    const u16* p2 = p1 + (size_t)32 * Ln * 64;
    float inv = 1.0f / (lpart[(size_t)sb0 * Ln + rg] +
                        lpart[(size_t)(sb0 + 32) * Ln + rg]);
    uint4 a1 = *(const uint4*)p1, c1 = *(const uint4*)p2;
    uint4 a2 = *(const uint4*)(p1 + 8), c2 = *(const uint4*)(p2 + 8);
    uint4 r1, r2;
    r1.x = pkbf((bflo(a1.x) + bflo(c1.x)) * inv, (bfhi(a1.x) + bfhi(c1.x)) * inv);
    r1.y = pkbf((bflo(a1.y) + bflo(c1.y)) * inv, (bfhi(a1.y) + bfhi(c1.y)) * inv);
    r1.z = pkbf((bflo(a1.z) + bflo(c1.z)) * inv, (bfhi(a1.z) + bfhi(c1.z)) * inv);
    r1.w = pkbf((bflo(a1.w) + bflo(c1.w)) * inv, (bfhi(a1.w) + bfhi(c1.w)) * inv);
    r2.x = pkbf((bflo(a2.x) + bflo(c2.x)) * inv, (bfhi(a2.x) + bfhi(c2.x)) * inv);
    r2.y = pkbf((bflo(a2.y) + bflo(c2.y)) * inv, (bfhi(a2.y) + bfhi(c2.y)) * inv);
    r2.z = pkbf((bflo(a2.z) + bflo(c2.z)) * inv, (bfhi(a2.z) + bfhi(c2.z)) * inv);
    r2.w = pkbf((bflo(a2.w) + bflo(c2.w)) * inv, (bfhi(a2.w) + bfhi(c2.w)) * inv);
    *(uint4*)&Bs[row * 32 + (((half * 2) ^ ssw) * 8)] = r1;
    *(uint4*)&Bs[row * 32 + (((half * 2 + 1) ^ ssw) * 8)] = r2;
    __syncthreads();
    bfrag af[2], bfv[4];
    for (int mi = 0; mi < 2; mi++)
      af[mi] = *(const bfrag*)&As[(mw + mi * 16 + lo) * 32 + ((quad ^ rsw) * 8)];
    for (int ni = 0; ni < 4; ni++)
      bfv[ni] = *(const bfrag*)&Bs[(nw + ni * 16 + lo) * 32 + ((quad ^ rsw) * 8)];
    for (int mi = 0; mi < 2; mi++)
      for (int ni = 0; ni < 4; ni++)
        acc[mi][ni] = mfma16(af[mi], bfv[ni], acc[mi][ni]);
    __syncthreads();
  }
  for (int mi = 0; mi < 2; mi++) {
    int cb = m0 + mw + mi * 16 + quad * 4;
    for (int r = 0; r < 4; r++) {
      float bias = wb[cb + r];
      float s = 0.f, q = 0.f;
      for (int ni = 0; ni < 4; ni++) {
        float v = acc[mi][ni][r] + bias;
        wy[((size_t)b * Cn + cb + r) * Ln + n0 + nw + ni * 16 + lo] = f2bf_fast(v);
        s += v; q += v * v;  // stats from fp32 pre-round values
      }
      for (int mask = 1; mask < 16; mask <<= 1) {
        s += __shfl_xor(s, mask);
        q += __shfl_xor(q, mask);
      }
      if (lo == 0) {
        atomicAdd(&stats[cb + r], s);
        atomicAdd(&stats[Cn + cb + r], q);
      }
    }
  }
}

// ---------------- kernel 5: BN apply (bf16 in, f32 out) ----------------
__global__ void k_bn(const u16* __restrict__ wy, const float* __restrict__ stats,
                     const float* __restrict__ gam, const float* __restrict__ bet,
                     float* __restrict__ out) {
  int i = blockIdx.x * 256 + threadIdx.x;
  size_t idx = (size_t)i * 8;
  int c = (int)((idx >> 11) & (Cn - 1));  // [B,C,L], L=2^11
  const float invN = 1.f / (Bn * Ln);
  float mean = stats[c] * invN;
  float var = stats[Cn + c] * invN - mean * mean;
  float scl = gam[c] * rsqrtf(var + 1e-5f);
  float sh = bet[c] - mean * scl;
  uint4 v = *(const uint4*)(wy + idx);
  float4 o0, o1;
  o0.x = bflo(v.x) * scl + sh; o0.y = bfhi(v.x) * scl + sh;
  o0.z = bflo(v.y) * scl + sh; o0.w = bfhi(v.y) * scl + sh;
  o1.x = bflo(v.z) * scl + sh; o1.y = bfhi(v.z) * scl + sh;
  o1.z = bflo(v.w) * scl + sh; o1.w = bfhi(v.w) * scl + sh;
  *(float4*)(out + idx) = o0;
  *(float4*)(out + idx + 4) = o1;
}

extern "C" void kernel_launch(void* const* d_in, const int* in_sizes, int n_in,
                              void* d_out, int out_size, void* d_ws, size_t ws_size,
                              hipStream_t stream) {
  const float* x   = (const float*)d_in[0];
  const float* g_w = (const float*)d_in[1];
  const float* g_b = (const float*)d_in[2];
  const float* t_w = (const float*)d_in[3];
  const float* t_b = (const float*)d_in[4];
  const float* p_w = (const float*)d_in[5];
  const float* p_b = (const float*)d_in[6];
  const float* w_w = (const float*)d_in[7];
  const float* w_b = (const float*)d_in[8];
  const float* gam = (const float*)d_in[9];
  const float* bet = (const float*)d_in[10];
  float* out = (float*)d_out;

  char* ws = (char*)d_ws;
  size_t off = 0;
  auto alloc = [&](size_t bytes) {
    char* p = ws + off; off += (bytes + 255) & ~(size_t)255; return p;
  };
  u16*  xT   = (u16*)alloc((size_t)Bn * Ln * Cn * 2);      // x^T bf16        8.4MB
  u16*  Wcat = (u16*)alloc((size_t)COn * Cn * 2);          // [theta;phi;g]   1.6MB
  u16*  Ww   = (u16*)alloc((size_t)Cn * CIn * 2);          // w_w bf16        0.5MB
  u16*  Qb   = (u16*)alloc((size_t)Bn * Hn * Ln * Dn * 2); // theta [B,H,L,D] 8.4MB
  u16*  Kb   = (u16*)alloc((size_t)Bn * Hn * Ln * Dn * 2); // phi   [B,H,L,D] 8.4MB
  u16*  Vt   = (u16*)alloc((size_t)Bn * Hn * Dn * Ln * 2); // g     [B,H,D,L] 8.4MB
  u16*  Opart = (u16*)alloc((size_t)2 * 32 * Ln * 64 * 2); // attn partials  16.8MB
  float* lpart = (float*)alloc((size_t)2 * 32 * Ln * 4);   // split l sums    0.5MB
  u16*  wy   = (u16*)alloc((size_t)Bn * Cn * Ln * 2);      // pre-BN bf16     8.4MB
  float* st  = (float*)alloc(2 * Cn * 4);                  // BN sum/sumsq
  if (ws_size < off) return;  // ~61.5 MB required (same as R4)

  k_misc<<<dim3(64, 16, 5), 256, 0, stream>>>(x, g_w, t_w, p_w, w_w, xT, Wcat, Ww, st);
  k_proj<<<dim3(16, 12, 4), 256, 0, stream>>>(Wcat, xT, t_b, p_b, g_b, Qb, Kb, Vt);
  k_attn<<<dim3(16, 16, 4), 256, 0, stream>>>(Qb, Kb, Vt, Opart, lpart);
  k_wgemm<<<dim3(16, 8, 4), 256, 0, stream>>>(Ww, Opart, lpart, w_b, wy, st);
  k_bn<<<dim3(2048), 256, 0, stream>>>(wy, st, gam, bet, out);
}

// Round 7
// 191.279 us; speedup vs baseline: 2.0015x; 1.0254x over previous
//
#include <hip/hip_runtime.h>

// Problem constants (match reference)
constexpr int Bn = 4, Cn = 512, Ln = 2048, CIn = 512, Hn = 8, Dn = 64;
constexpr int COn = 3 * CIn;  // 1536 stacked output channels: [theta; phi; g]

typedef unsigned short u16;
typedef unsigned int u32;
typedef __attribute__((ext_vector_type(8))) short bfrag;  // 8 x bf16 (4 VGPRs)
typedef __attribute__((ext_vector_type(4))) float facc;   // 4 x f32 acc

// 1/sqrt(D) * log2(e): folded into theta weights/bias so QK^T lands in log2 domain
#define SCF 0.180336879f

__device__ __forceinline__ facc mfma16(bfrag a, bfrag b, facc c) {
  return __builtin_amdgcn_mfma_f32_16x16x32_bf16(a, b, c, 0, 0, 0);
}

__device__ __forceinline__ void async16(const void* g, void* l) {
  __builtin_amdgcn_global_load_lds((const __attribute__((address_space(1))) void*)g,
                                   (__attribute__((address_space(3))) void*)l, 16, 0, 0);
}

__device__ __forceinline__ u16 f2bf(float x) {  // RNE float->bf16
  union { float f; u32 u; } v; v.f = x;
  u32 r = v.u + 0x7FFFu + ((v.u >> 16) & 1u);
  return (u16)(r >> 16);
}

__device__ __forceinline__ u16 f2bf_fast(float x) {  // round-half-up, 2 ops
  union { float f; u32 u; } v; v.f = x;
  return (u16)((v.u + 0x8000u) >> 16);
}

// pack 2 floats -> bf16x2 in one u32: 2 round-adds + 1 v_perm
__device__ __forceinline__ u32 pkbf(float lof, float hif) {
  union { float f; u32 u; } a, b; a.f = lof; b.f = hif;
  return __builtin_amdgcn_perm(b.u + 0x8000u, a.u + 0x8000u, 0x07060302u);
}

__device__ __forceinline__ float bflo(u32 u) { return __uint_as_float(u << 16); }
__device__ __forceinline__ float bfhi(u32 u) { return __uint_as_float(u & 0xFFFF0000u); }

// Swizzled frag read for row-stride-64-u16 (128B) tiles: granule gi (16B units)
// of row `row` lives at position gi ^ (row&7). Conflict-free b128 reads.
__device__ __forceinline__ bfrag fr8(const u16* base, int row, int gi) {
  return *(const bfrag*)&base[row * 64 + ((gi ^ (row & 7)) * 8)];
}

// ------- kernel 1: fused weights->bf16 + BN-stat zero + x transpose -------
// grid (64,16,5): z<4 -> xpose batch z; z==4 -> weight convert (1024 blocks).
__global__ void k_misc(const float* __restrict__ x, const float* __restrict__ gw,
                       const float* __restrict__ tw, const float* __restrict__ pw,
                       const float* __restrict__ ww, u16* __restrict__ xT,
                       u16* __restrict__ Wcat, u16* __restrict__ Ww,
                       float* __restrict__ stats) {
  int b = blockIdx.z;
  if (b == 4) {  // weight convert path
    int i = (blockIdx.y * 64 + blockIdx.x) * 256 + threadIdx.x;
    if (i < CIn * Cn) {
      Wcat[i]                = f2bf(tw[i] * SCF);  // theta (Q), pre-scaled
      Wcat[CIn * Cn + i]     = f2bf(pw[i]);        // phi   (K)
      Wcat[2 * CIn * Cn + i] = f2bf(gw[i]);        // g     (V)
      Ww[i]                  = f2bf(ww[i]);
    }
    if (i < 2 * Cn) stats[i] = 0.f;  // d_ws is poisoned each launch
    return;
  }
  __shared__ float tile[32][33];
  int l0 = blockIdx.x * 32, c0 = blockIdx.y * 32;
  int tx = threadIdx.x & 31, ty = threadIdx.x >> 5;
  const float* xb = x + (size_t)b * Cn * Ln;
  for (int k = 0; k < 4; k++)
    tile[ty + k * 8][tx] = xb[(size_t)(c0 + ty + k * 8) * Ln + l0 + tx];
  __syncthreads();
  u16* xtb = xT + (size_t)b * Ln * Cn;
  int cc = (threadIdx.x & 15) * 2, r0 = threadIdx.x >> 4;
  for (int k = 0; k < 2; k++) {
    int ll = r0 + k * 16;
    u32 pk = pkbf(tile[cc][ll], tile[cc + 1][ll]);
    *(u32*)&xtb[(size_t)(l0 + ll) * Cn + c0 + cc] = pk;
  }
}

// ------------- GEMM core: C[128,128] = A[128,K] * Bt[128,K]^T -------------
__device__ __forceinline__ void stage128x32(const u16* g, int K, int k0, u16* lds,
                                            int w, int l) {
  int gsw = ((l & 3) ^ ((l >> 3) & 3)) * 8;
  for (int jj = 0; jj < 2; jj++) {
    int j = w * 2 + jj;
    const u16* ga = g + (size_t)(j * 16 + (l >> 2)) * K + k0 + gsw;
    async16(ga, (char*)lds + j * 1024 + l * 16);
  }
}

// SWAP=1 computes C^T tiles (A-operand = Bt rows) for packed transposed stores.
template <int SWAP>
__device__ __forceinline__ void gemm_core(const u16* A, const u16* Bt, int K,
                                          u16* As, u16* Bs, facc acc[4][4],
                                          int w, int l) {
  int quad = l >> 4, lo = l & 15;
  int mw = (w >> 1) * 64, nw = (w & 1) * 64;
  int rsw = (lo >> 1) & 3;
  for (int k0 = 0; k0 < K; k0 += 32) {
    stage128x32(A, K, k0, As, w, l);
    stage128x32(Bt, K, k0, Bs, w, l);
    __syncthreads();
    bfrag af[4], bfv[4];
    for (int mi = 0; mi < 4; mi++)
      af[mi] = *(const bfrag*)&As[(mw + mi * 16 + lo) * 32 + ((quad ^ rsw) * 8)];
    for (int ni = 0; ni < 4; ni++)
      bfv[ni] = *(const bfrag*)&Bs[(nw + ni * 16 + lo) * 32 + ((quad ^ rsw) * 8)];
    for (int mi = 0; mi < 4; mi++)
      for (int ni = 0; ni < 4; ni++)
        acc[mi][ni] = SWAP ? mfma16(bfv[ni], af[mi], acc[mi][ni])
                           : mfma16(af[mi], bfv[ni], acc[mi][ni]);
    __syncthreads();
  }
}

// 64xK * Bt[128,K]^T variant (for k_wgemm)
__device__ __forceinline__ void gemm_core64(const u16* A, const u16* Bt, int K,
                                            u16* As, u16* Bs, facc acc[2][4],
                                            int w, int l) {
  int quad = l >> 4, lo = l & 15;
  int mw = (w >> 1) * 32, nw = (w & 1) * 64;
  int rsw = (lo >> 1) & 3;
  int gsw = ((l & 3) ^ ((l >> 3) & 3)) * 8;
  for (int k0 = 0; k0 < K; k0 += 32) {
    async16(A + (size_t)(w * 16 + (l >> 2)) * K + k0 + gsw, (char*)As + w * 1024 + l * 16);
    stage128x32(Bt, K, k0, Bs, w, l);
    __syncthreads();
    bfrag af[2], bfv[4];
    for (int mi = 0; mi < 2; mi++)
      af[mi] = *(const bfrag*)&As[(mw + mi * 16 + lo) * 32 + ((quad ^ rsw) * 8)];
    for (int ni = 0; ni < 4; ni++)
      bfv[ni] = *(const bfrag*)&Bs[(nw + ni * 16 + lo) * 32 + ((quad ^ rsw) * 8)];
    for (int mi = 0; mi < 2; mi++)
      for (int ni = 0; ni < 4; ni++)
        acc[mi][ni] = mfma16(af[mi], bfv[ni], acc[mi][ni]);
    __syncthreads();
  }
}

// ---------------- kernel 2: fused projection GEMM + head-split epilogue ----------------
__global__ __launch_bounds__(256) void k_proj(
    const u16* __restrict__ Wcat, const u16* __restrict__ xT,
    const float* __restrict__ tb, const float* __restrict__ pb,
    const float* __restrict__ gb, u16* __restrict__ Q, u16* __restrict__ Kb,
    u16* __restrict__ Vt) {
  __shared__ __align__(16) u16 As[128 * 32];
  __shared__ __align__(16) u16 Bs[128 * 32];
  int w = threadIdx.x >> 6, l = threadIdx.x & 63;
  int quad = l >> 4, lo = l & 15;
  int m0 = blockIdx.y * 128, n0 = blockIdx.x * 128, b = blockIdx.z;
  int chunk = m0 >> 9;  // 128-tiles never straddle 512-row chunks
  facc acc[4][4] = {};
  const u16* Ap = Wcat + (size_t)m0 * Cn;
  const u16* Bp = xT + ((size_t)b * Ln + n0) * Cn;
  int mw = (w >> 1) * 64, nw = (w & 1) * 64;
  if (chunk < 2) {
    gemm_core<0>(Ap, Bp, Cn, As, Bs, acc, w, l);
    const float* bias = (chunk == 0) ? tb : pb;
    float bs = (chunk == 0) ? SCF : 1.0f;
    for (int mi = 0; mi < 4; mi++) {
      int mo = (m0 + mw + mi * 16) & 511;
      int hh = mo >> 6;
      int db = (mo & 63) + quad * 4;
      int bi = mo + quad * 4;
      u16* dst0 = ((chunk == 0) ? Q : Kb) + (size_t)(b * Hn + hh) * Ln * 64 + db;
      float b0 = bias[bi] * bs, b1 = bias[bi + 1] * bs;
      float b2 = bias[bi + 2] * bs, b3 = bias[bi + 3] * bs;
      for (int ni = 0; ni < 4; ni++) {
        int lcol = n0 + nw + ni * 16 + lo;
        facc a = acc[mi][ni];
        uint2 pk;
        pk.x = pkbf(a[0] + b0, a[1] + b1);
        pk.y = pkbf(a[2] + b2, a[3] + b3);
        *(uint2*)(dst0 + (size_t)lcol * 64) = pk;
      }
    }
  } else {  // g -> Vt [B,H,D,L], transposed accumulation, packed-l stores
    gemm_core<1>(Ap, Bp, Cn, As, Bs, acc, w, l);
    for (int mi = 0; mi < 4; mi++) {
      int ch = (m0 + mw + mi * 16 + lo) & 511;  // channel per lane
      int hh = ch >> 6, d = ch & 63;
      float bias = gb[ch];
      u16* dst0 = Vt + ((size_t)(b * Hn + hh) * Dn + d) * Ln;
      for (int ni = 0; ni < 4; ni++) {
        int l0 = n0 + nw + ni * 16 + quad * 4;  // 4 consecutive l in acc regs
        facc a = acc[mi][ni];
        uint2 pk;
        pk.x = pkbf(a[0] + bias, a[1] + bias);
        pk.y = pkbf(a[2] + bias, a[3] + bias);
        *(uint2*)(dst0 + l0) = pk;
      }
    }
  }
}

// ---------------- kernel 3: flash attention, fixed-max softmax, split-K x3 ----------------
// R4-proven inner loop. Split x3 -> grid 1536 = 2 exact co-residency rounds at
// 3 blocks/CU (48KB LDS): no 1/3-occupancy tail. Tiles 11/11/10 of 64 kpos.
// Fixed-max (|s|~1 in log2 domain): partials exactly linear, un-normalized bf16.
__global__ __launch_bounds__(256, 2) void k_attn(
    const u16* __restrict__ Q, const u16* __restrict__ Kb,
    const u16* __restrict__ Vt, u16* __restrict__ Opart,
    float* __restrict__ lpart) {
  __shared__ __align__(16) u16 lds[24576];  // Ks[2][4096] | Vs[2][4096] | QPs[8192]
  u16* Ks = lds;
  u16* Vs = lds + 8192;
  u16* QPs = lds + 16384;
  int w = threadIdx.x >> 6, l = threadIdx.x & 63;
  int quad = l >> 4, lo = l & 15;
  int q0 = blockIdx.x * 128, b = blockIdx.z;
  int h = blockIdx.y / 3, split = blockIdx.y - h * 3;
  int ts = split * 11;                       // start tile (64 kpos each)
  int nt = (split == 2) ? 10 : 11;           // tiles this split
  size_t bh = (size_t)b * Hn + h;
  const u16* Qg = Q + bh * Ln * 64;
  const u16* Kg = Kb + bh * Ln * 64 + (size_t)ts * 4096;  // + ts*64 rows
  const u16* Vg = Vt + bh * (size_t)Dn * Ln + ts * 64;    // + ts*64 cols

  int rin = l >> 3;
  int gg = ((l & 7) ^ rin) * 8;

  for (int jj = 0; jj < 4; jj++) {  // wave stages its OWN 32 Q rows
    int j = w * 4 + jj;
    async16(Qg + (size_t)(q0 + j * 8 + rin) * 64 + gg, (char*)QPs + j * 1024 + l * 16);
  }
  for (int jj = 0; jj < 2; jj++) {  // K/V tile 0 -> buf 0
    int j = w * 2 + jj;
    async16(Kg + (size_t)(j * 8 + rin) * 64 + gg, (char*)Ks + j * 1024 + l * 16);
    async16(Vg + (size_t)(j * 8 + rin) * Ln + gg, (char*)Vs + j * 1024 + l * 16);
  }
  __syncthreads();
  bfrag qf[2][2];  // wave-private rows, hoisted before P overwrites QPs
  for (int s = 0; s < 2; s++)
    for (int c = 0; c < 2; c++)
      qf[s][c] = fr8(QPs, w * 32 + s * 16 + lo, c * 4 + quad);

  facc o[2][4] = {};  // O^T[d = mi*16+quad*4+r][q = qset*16+lo]
  float l_i[2] = {0.f, 0.f};

  for (int t = 0; t < nt; t++) {
    const u16* Kc = Ks + (t & 1) * 4096;
    const u16* Vc = Vs + (t & 1) * 4096;
    if (t < nt - 1) {  // prefetch next tile into other buffer
      int nb = (~t & 1) * 4096;
      int kbase = (t + 1) * 64;
      for (int jj = 0; jj < 2; jj++) {
        int j = w * 2 + jj;
        async16(Kg + (size_t)(kbase + j * 8 + rin) * 64 + gg,
                (char*)(Ks + nb) + j * 1024 + l * 16);
        async16(Vg + (size_t)(j * 8 + rin) * Ln + kbase + gg,
                (char*)(Vs + nb) + j * 1024 + l * 16);
      }
    }
    for (int ni = 0; ni < 4; ni++) {
      bfrag kf0 = fr8(Kc, ni * 16 + lo, quad);
      bfrag kf1 = fr8(Kc, ni * 16 + lo, 4 + quad);
      for (int s = 0; s < 2; s++) {
        facc z = {};
        facc stv = mfma16(kf1, qf[s][1], mfma16(kf0, qf[s][0], z));
        float p0 = __builtin_amdgcn_exp2f(stv[0]);
        float p1 = __builtin_amdgcn_exp2f(stv[1]);
        float p2 = __builtin_amdgcn_exp2f(stv[2]);
        float p3 = __builtin_amdgcn_exp2f(stv[3]);
        l_i[s] += (p0 + p1) + (p2 + p3);
        int row = w * 32 + s * 16 + lo;
        uint2 pk;
        pk.x = pkbf(p0, p1);
        pk.y = pkbf(p2, p3);
        int gi = ni * 2 + (quad >> 1);
        *(uint2*)&QPs[row * 64 + ((gi ^ (row & 7)) * 8) + (quad & 1) * 4] = pk;
      }
    }
    bfrag pb2[2][2];
    for (int s = 0; s < 2; s++)
      for (int c = 0; c < 2; c++)
        pb2[s][c] = fr8(QPs, w * 32 + s * 16 + lo, c * 4 + quad);
    for (int mi = 0; mi < 4; mi++) {
      bfrag vf0 = fr8(Vc, mi * 16 + lo, quad);
      bfrag vf1 = fr8(Vc, mi * 16 + lo, 4 + quad);
      for (int s = 0; s < 2; s++)
        o[s][mi] = mfma16(vf1, pb2[s][1], mfma16(vf0, pb2[s][0], o[s][mi]));
    }
    __syncthreads();
  }
  // epilogue: un-normalized O partial (bf16) + l partial (f32)
  int sb = split * 32 + (int)bh;  // [split][bh]
  for (int s = 0; s < 2; s++) {
    float lt = l_i[s];
    lt += __shfl_xor(lt, 16);
    lt += __shfl_xor(lt, 32);
    int q = q0 + w * 32 + s * 16 + lo;
    u16* dst = Opart + ((size_t)sb * Ln + q) * 64;
    for (int mi = 0; mi < 4; mi++) {
      uint2 pk;
      pk.x = pkbf(o[s][mi][0], o[s][mi][1]);
      pk.y = pkbf(o[s][mi][2], o[s][mi][3]);
      *(uint2*)(dst + mi * 16 + quad * 4) = pk;
    }
    if (quad == 0) lpart[(size_t)sb * Ln + q] = lt;
  }
}

// ---------------- kernel 4: combine 3 split-K partials -> yT [B,L,CI] bf16 ----------------
__global__ void k_comb(const u16* __restrict__ Opart, const float* __restrict__ lpart,
                       u16* __restrict__ yT) {
  int i = blockIdx.x * 256 + threadIdx.x;  // 524288 threads, 8 d each
  int bhq = i >> 3, d0 = (i & 7) * 8;
  int bh = bhq >> 11, q = bhq & 2047;
  const u16* o1 = Opart + ((size_t)bh * Ln + q) * 64 + d0;
  const u16* o2 = o1 + (size_t)32 * Ln * 64;
  const u16* o3 = o2 + (size_t)32 * Ln * 64;
  float inv = 1.0f / (lpart[bhq] + lpart[65536 + bhq] + lpart[131072 + bhq]);
  uint4 a = *(const uint4*)o1, c = *(const uint4*)o2, e = *(const uint4*)o3;
  uint4 r;
  r.x = pkbf((bflo(a.x) + bflo(c.x) + bflo(e.x)) * inv,
             (bfhi(a.x) + bfhi(c.x) + bfhi(e.x)) * inv);
  r.y = pkbf((bflo(a.y) + bflo(c.y) + bflo(e.y)) * inv,
             (bfhi(a.y) + bfhi(c.y) + bfhi(e.y)) * inv);
  r.z = pkbf((bflo(a.z) + bflo(c.z) + bflo(e.z)) * inv,
             (bfhi(a.z) + bfhi(c.z) + bfhi(e.z)) * inv);
  r.w = pkbf((bflo(a.w) + bflo(c.w) + bflo(e.w)) * inv,
             (bfhi(a.w) + bfhi(c.w) + bfhi(e.w)) * inv);
  int b = bh >> 3, h = bh & 7;
  *(uint4*)(yT + ((size_t)b * Ln + q) * CIn + h * 64 + d0) = r;
}

// ---------------- kernel 5: W GEMM (64x128 tiles) + BN statistics ----------------
__global__ __launch_bounds__(256) void k_wgemm(
    const u16* __restrict__ Ww, const u16* __restrict__ yT,
    const float* __restrict__ wb, u16* __restrict__ wy,
    float* __restrict__ stats) {
  __shared__ __align__(16) u16 As[64 * 32];
  __shared__ __align__(16) u16 Bs[128 * 32];
  int w = threadIdx.x >> 6, l = threadIdx.x & 63;
  int quad = l >> 4, lo = l & 15;
  int m0 = blockIdx.y * 64, n0 = blockIdx.x * 128, b = blockIdx.z;
  facc acc[2][4] = {};
  gemm_core64(Ww + (size_t)m0 * CIn, yT + ((size_t)b * Ln + n0) * CIn, CIn, As, Bs, acc, w, l);
  int mw = (w >> 1) * 32, nw = (w & 1) * 64;
  for (int mi = 0; mi < 2; mi++) {
    int cb = m0 + mw + mi * 16 + quad * 4;
    for (int r = 0; r < 4; r++) {
      float bias = wb[cb + r];
      float s = 0.f, q = 0.f;
      for (int ni = 0; ni < 4; ni++) {
        float v = acc[mi][ni][r] + bias;
        wy[((size_t)b * Cn + cb + r) * Ln + n0 + nw + ni * 16 + lo] = f2bf_fast(v);
        s += v; q += v * v;  // stats from fp32 pre-round values
      }
      for (int mask = 1; mask < 16; mask <<= 1) {
        s += __shfl_xor(s, mask);
        q += __shfl_xor(q, mask);
      }
      if (lo == 0) {
        atomicAdd(&stats[cb + r], s);
        atomicAdd(&stats[Cn + cb + r], q);
      }
    }
  }
}

// ---------------- kernel 6: BN apply (bf16 in, f32 out) ----------------
__global__ void k_bn(const u16* __restrict__ wy, const float* __restrict__ stats,
                     const float* __restrict__ gam, const float* __restrict__ bet,
                     float* __restrict__ out) {
  int i = blockIdx.x * 256 + threadIdx.x;
  size_t idx = (size_t)i * 8;
  int c = (int)((idx >> 11) & (Cn - 1));  // [B,C,L], L=2^11
  const float invN = 1.f / (Bn * Ln);
  float mean = stats[c] * invN;
  float var = stats[Cn + c] * invN - mean * mean;
  float scl = gam[c] * rsqrtf(var + 1e-5f);
  float sh = bet[c] - mean * scl;
  uint4 v = *(const uint4*)(wy + idx);
  float4 o0, o1;
  o0.x = bflo(v.x) * scl + sh; o0.y = bfhi(v.x) * scl + sh;
  o0.z = bflo(v.y) * scl + sh; o0.w = bfhi(v.y) * scl + sh;
  o1.x = bflo(v.z) * scl + sh; o1.y = bfhi(v.z) * scl + sh;
  o1.z = bflo(v.w) * scl + sh; o1.w = bfhi(v.w) * scl + sh;
  *(float4*)(out + idx) = o0;
  *(float4*)(out + idx + 4) = o1;
}

extern "C" void kernel_launch(void* const* d_in, const int* in_sizes, int n_in,
                              void* d_out, int out_size, void* d_ws, size_t ws_size,
                              hipStream_t stream) {
  const float* x   = (const float*)d_in[0];
  const float* g_w = (const float*)d_in[1];
  const float* g_b = (const float*)d_in[2];
  const float* t_w = (const float*)d_in[3];
  const float* t_b = (const float*)d_in[4];
  const float* p_w = (const float*)d_in[5];
  const float* p_b = (const float*)d_in[6];
  const float* w_w = (const float*)d_in[7];
  const float* w_b = (const float*)d_in[8];
  const float* gam = (const float*)d_in[9];
  const float* bet = (const float*)d_in[10];
  float* out = (float*)d_out;

  char* ws = (char*)d_ws;
  size_t off = 0;
  auto alloc = [&](size_t bytes) {
    char* p = ws + off; off += (bytes + 255) & ~(size_t)255; return p;
  };
  u16*  xT   = (u16*)alloc((size_t)Bn * Ln * Cn * 2);      // x^T bf16        8.4MB
  u16*  Wcat = (u16*)alloc((size_t)COn * Cn * 2);          // [theta;phi;g]   1.6MB
  u16*  Ww   = (u16*)alloc((size_t)Cn * CIn * 2);          // w_w bf16        0.5MB
  u16*  Qb   = (u16*)alloc((size_t)Bn * Hn * Ln * Dn * 2); // theta [B,H,L,D] 8.4MB
  u16*  Kb   = (u16*)alloc((size_t)Bn * Hn * Ln * Dn * 2); // phi   [B,H,L,D] 8.4MB
  u16*  Vt   = (u16*)alloc((size_t)Bn * Hn * Dn * Ln * 2); // g     [B,H,D,L] 8.4MB
  u16*  Opart = (u16*)alloc((size_t)3 * 32 * Ln * 64 * 2); // attn partials  25.2MB
  float* lpart = (float*)alloc((size_t)3 * 32 * Ln * 4);   // split l sums    0.8MB
  float* st  = (float*)alloc(2 * Cn * 4);                  // BN sum/sumsq
  // Aliases into buffers dead after k_attn: yT <- Kb, wy <- Qb (same sizes).
  u16* yT = Kb;   // written by k_comb, read by k_wgemm
  u16* wy = Qb;   // written by k_wgemm, read by k_bn
  if (ws_size < off) return;  // ~62 MB required (same footprint as R6)

  k_misc<<<dim3(64, 16, 5), 256, 0, stream>>>(x, g_w, t_w, p_w, w_w, xT, Wcat, Ww, st);
  k_proj<<<dim3(16, 12, 4), 256, 0, stream>>>(Wcat, xT, t_b, p_b, g_b, Qb, Kb, Vt);
  k_attn<<<dim3(16, 24, 4), 256, 0, stream>>>(Qb, Kb, Vt, Opart, lpart);
  k_comb<<<dim3(2048), 256, 0, stream>>>(Opart, lpart, yT);
  k_wgemm<<<dim3(16, 8, 4), 256, 0, stream>>>(Ww, yT, w_b, wy, st);
  k_bn<<<dim3(2048), 256, 0, stream>>>(wy, st, gam, bet, out);
}

// Round 9
// 188.721 us; speedup vs baseline: 2.0287x; 1.0136x over previous
//
#include <hip/hip_runtime.h>

// Problem constants (match reference)
constexpr int Bn = 4, Cn = 512, Ln = 2048, CIn = 512, Hn = 8, Dn = 64;
constexpr int COn = 3 * CIn;  // 1536 stacked output channels: [theta; phi; g]

typedef unsigned short u16;
typedef unsigned int u32;
typedef __attribute__((ext_vector_type(8))) short bfrag;  // 8 x bf16 (4 VGPRs)
typedef __attribute__((ext_vector_type(4))) float facc;   // 4 x f32 acc

// 1/sqrt(D) * log2(e): folded into theta weights/bias so QK^T lands in log2 domain
#define SCF 0.180336879f

__device__ __forceinline__ facc mfma16(bfrag a, bfrag b, facc c) {
  return __builtin_amdgcn_mfma_f32_16x16x32_bf16(a, b, c, 0, 0, 0);
}

__device__ __forceinline__ void async16(const void* g, void* l) {
  __builtin_amdgcn_global_load_lds((const __attribute__((address_space(1))) void*)g,
                                   (__attribute__((address_space(3))) void*)l, 16, 0, 0);
}

__device__ __forceinline__ u16 f2bf(float x) {  // RNE float->bf16
  union { float f; u32 u; } v; v.f = x;
  u32 r = v.u + 0x7FFFu + ((v.u >> 16) & 1u);
  return (u16)(r >> 16);
}

__device__ __forceinline__ u16 f2bf_fast(float x) {  // round-half-up, 2 ops
  union { float f; u32 u; } v; v.f = x;
  return (u16)((v.u + 0x8000u) >> 16);
}

// pack 2 floats -> bf16x2 in one u32: 2 round-adds + 1 v_perm
__device__ __forceinline__ u32 pkbf(float lof, float hif) {
  union { float f; u32 u; } a, b; a.f = lof; b.f = hif;
  return __builtin_amdgcn_perm(b.u + 0x8000u, a.u + 0x8000u, 0x07060302u);
}

__device__ __forceinline__ float bflo(u32 u) { return __uint_as_float(u << 16); }
__device__ __forceinline__ float bfhi(u32 u) { return __uint_as_float(u & 0xFFFF0000u); }

// Swizzled frag read for row-stride-64-u16 (128B) tiles: granule gi (16B units)
// of row `row` lives at position gi ^ (row&7). Conflict-free b128 reads.
__device__ __forceinline__ bfrag fr8(const u16* base, int row, int gi) {
  return *(const bfrag*)&base[row * 64 + ((gi ^ (row & 7)) * 8)];
}

// ------- kernel 1: fused weights->bf16 + BN-stat zero + x transpose -------
// grid (64,16,5): z<4 -> xpose batch z; z==4 -> weight convert (1024 blocks).
__global__ void k_misc(const float* __restrict__ x, const float* __restrict__ gw,
                       const float* __restrict__ tw, const float* __restrict__ pw,
                       const float* __restrict__ ww, u16* __restrict__ xT,
                       u16* __restrict__ Wcat, u16* __restrict__ Ww,
                       float* __restrict__ stats) {
  int b = blockIdx.z;
  if (b == 4) {  // weight convert path
    int i = (blockIdx.y * 64 + blockIdx.x) * 256 + threadIdx.x;
    if (i < CIn * Cn) {
      Wcat[i]                = f2bf(tw[i] * SCF);  // theta (Q), pre-scaled
      Wcat[CIn * Cn + i]     = f2bf(pw[i]);        // phi   (K)
      Wcat[2 * CIn * Cn + i] = f2bf(gw[i]);        // g     (V)
      Ww[i]                  = f2bf(ww[i]);
    }
    if (i < 2 * Cn) stats[i] = 0.f;  // d_ws is poisoned each launch
    return;
  }
  __shared__ float tile[32][33];
  int l0 = blockIdx.x * 32, c0 = blockIdx.y * 32;
  int tx = threadIdx.x & 31, ty = threadIdx.x >> 5;
  const float* xb = x + (size_t)b * Cn * Ln;
  for (int k = 0; k < 4; k++)
    tile[ty + k * 8][tx] = xb[(size_t)(c0 + ty + k * 8) * Ln + l0 + tx];
  __syncthreads();
  u16* xtb = xT + (size_t)b * Ln * Cn;
  int cc = (threadIdx.x & 15) * 2, r0 = threadIdx.x >> 4;
  for (int k = 0; k < 2; k++) {
    int ll = r0 + k * 16;
    u32 pk = pkbf(tile[cc][ll], tile[cc + 1][ll]);
    *(u32*)&xtb[(size_t)(l0 + ll) * Cn + c0 + cc] = pk;
  }
}

// ------------- GEMM core: C[128,128] = A[128,K] * Bt[128,K]^T -------------
__device__ __forceinline__ void stage128x32(const u16* g, int K, int k0, u16* lds,
                                            int w, int l) {
  int gsw = ((l & 3) ^ ((l >> 3) & 3)) * 8;
  for (int jj = 0; jj < 2; jj++) {
    int j = w * 2 + jj;
    const u16* ga = g + (size_t)(j * 16 + (l >> 2)) * K + k0 + gsw;
    async16(ga, (char*)lds + j * 1024 + l * 16);
  }
}

// SWAP=1 computes C^T tiles (A-operand = Bt rows) for packed transposed stores.
template <int SWAP>
__device__ __forceinline__ void gemm_core(const u16* A, const u16* Bt, int K,
                                          u16* As, u16* Bs, facc acc[4][4],
                                          int w, int l) {
  int quad = l >> 4, lo = l & 15;
  int mw = (w >> 1) * 64, nw = (w & 1) * 64;
  int rsw = (lo >> 1) & 3;
  for (int k0 = 0; k0 < K; k0 += 32) {
    stage128x32(A, K, k0, As, w, l);
    stage128x32(Bt, K, k0, Bs, w, l);
    __syncthreads();
    bfrag af[4], bfv[4];
    for (int mi = 0; mi < 4; mi++)
      af[mi] = *(const bfrag*)&As[(mw + mi * 16 + lo) * 32 + ((quad ^ rsw) * 8)];
    for (int ni = 0; ni < 4; ni++)
      bfv[ni] = *(const bfrag*)&Bs[(nw + ni * 16 + lo) * 32 + ((quad ^ rsw) * 8)];
    for (int mi = 0; mi < 4; mi++)
      for (int ni = 0; ni < 4; ni++)
        acc[mi][ni] = SWAP ? mfma16(bfv[ni], af[mi], acc[mi][ni])
                           : mfma16(af[mi], bfv[ni], acc[mi][ni]);
    __syncthreads();
  }
}

// 64xK * Bt[128,K]^T variant (for k_wgemm)
__device__ __forceinline__ void gemm_core64(const u16* A, const u16* Bt, int K,
                                            u16* As, u16* Bs, facc acc[2][4],
                                            int w, int l) {
  int quad = l >> 4, lo = l & 15;
  int mw = (w >> 1) * 32, nw = (w & 1) * 64;
  int rsw = (lo >> 1) & 3;
  int gsw = ((l & 3) ^ ((l >> 3) & 3)) * 8;
  for (int k0 = 0; k0 < K; k0 += 32) {
    async16(A + (size_t)(w * 16 + (l >> 2)) * K + k0 + gsw, (char*)As + w * 1024 + l * 16);
    stage128x32(Bt, K, k0, Bs, w, l);
    __syncthreads();
    bfrag af[2], bfv[4];
    for (int mi = 0; mi < 2; mi++)
      af[mi] = *(const bfrag*)&As[(mw + mi * 16 + lo) * 32 + ((quad ^ rsw) * 8)];
    for (int ni = 0; ni < 4; ni++)
      bfv[ni] = *(const bfrag*)&Bs[(nw + ni * 16 + lo) * 32 + ((quad ^ rsw) * 8)];
    for (int mi = 0; mi < 2; mi++)
      for (int ni = 0; ni < 4; ni++)
        acc[mi][ni] = mfma16(af[mi], bfv[ni], acc[mi][ni]);
    __syncthreads();
  }
}

// ---------------- kernel 2: fused projection GEMM + head-split epilogue ----------------
__global__ __launch_bounds__(256) void k_proj(
    const u16* __restrict__ Wcat, const u16* __restrict__ xT,
    const float* __restrict__ tb, const float* __restrict__ pb,
    const float* __restrict__ gb, u16* __restrict__ Q, u16* __restrict__ Kb,
    u16* __restrict__ Vt) {
  __shared__ __align__(16) u16 As[128 * 32];
  __shared__ __align__(16) u16 Bs[128 * 32];
  int w = threadIdx.x >> 6, l = threadIdx.x & 63;
  int quad = l >> 4, lo = l & 15;
  int m0 = blockIdx.y * 128, n0 = blockIdx.x * 128, b = blockIdx.z;
  int chunk = m0 >> 9;  // 128-tiles never straddle 512-row chunks
  facc acc[4][4] = {};
  const u16* Ap = Wcat + (size_t)m0 * Cn;
  const u16* Bp = xT + ((size_t)b * Ln + n0) * Cn;
  int mw = (w >> 1) * 64, nw = (w & 1) * 64;
  if (chunk < 2) {
    gemm_core<0>(Ap, Bp, Cn, As, Bs, acc, w, l);
    const float* bias = (chunk == 0) ? tb : pb;
    float bs = (chunk == 0) ? SCF : 1.0f;
    for (int mi = 0; mi < 4; mi++) {
      int mo = (m0 + mw + mi * 16) & 511;
      int hh = mo >> 6;
      int db = (mo & 63) + quad * 4;
      int bi = mo + quad * 4;
      u16* dst0 = ((chunk == 0) ? Q : Kb) + (size_t)(b * Hn + hh) * Ln * 64 + db;
      float b0 = bias[bi] * bs, b1 = bias[bi + 1] * bs;
      float b2 = bias[bi + 2] * bs, b3 = bias[bi + 3] * bs;
      for (int ni = 0; ni < 4; ni++) {
        int lcol = n0 + nw + ni * 16 + lo;
        facc a = acc[mi][ni];
        uint2 pk;
        pk.x = pkbf(a[0] + b0, a[1] + b1);
        pk.y = pkbf(a[2] + b2, a[3] + b3);
        *(uint2*)(dst0 + (size_t)lcol * 64) = pk;
      }
    }
  } else {  // g -> Vt [B,H,D,L], transposed accumulation, packed-l stores
    gemm_core<1>(Ap, Bp, Cn, As, Bs, acc, w, l);
    for (int mi = 0; mi < 4; mi++) {
      int ch = (m0 + mw + mi * 16 + lo) & 511;  // channel per lane
      int hh = ch >> 6, d = ch & 63;
      float bias = gb[ch];
      u16* dst0 = Vt + ((size_t)(b * Hn + hh) * Dn + d) * Ln;
      for (int ni = 0; ni < 4; ni++) {
        int l0 = n0 + nw + ni * 16 + quad * 4;  // 4 consecutive l in acc regs
        facc a = acc[mi][ni];
        uint2 pk;
        pk.x = pkbf(a[0] + bias, a[1] + bias);
        pk.y = pkbf(a[2] + bias, a[3] + bias);
        *(uint2*)(dst0 + l0) = pk;
      }
    }
  }
}

// ---------------- kernel 3: flash attention, fixed-max softmax, NO split ----------------
// R3-proven body (57.2 us): K-tile 64 dbuf, 48KB LDS, direct normalized yT
// write. One dispatch fewer than split-K+combine (R4/R7) for ~equal kernel
// time -- this round measures the per-dispatch overhead.
__global__ __launch_bounds__(256, 2) void k_attn(
    const u16* __restrict__ Q, const u16* __restrict__ Kb,
    const u16* __restrict__ Vt, u16* __restrict__ yT) {
  __shared__ __align__(16) u16 lds[24576];  // Ks[2][4096] | Vs[2][4096] | QPs[8192]
  u16* Ks = lds;
  u16* Vs = lds + 8192;
  u16* QPs = lds + 16384;
  int w = threadIdx.x >> 6, l = threadIdx.x & 63;
  int quad = l >> 4, lo = l & 15;
  int q0 = blockIdx.x * 128, h = blockIdx.y, b = blockIdx.z;
  size_t bh = (size_t)b * Hn + h;
  const u16* Qg = Q + bh * Ln * 64;
  const u16* Kg = Kb + bh * Ln * 64;
  const u16* Vg = Vt + bh * (size_t)Dn * Ln;

  int rin = l >> 3;
  int gg = ((l & 7) ^ rin) * 8;

  for (int jj = 0; jj < 4; jj++) {  // wave stages its OWN 32 Q rows
    int j = w * 4 + jj;
    async16(Qg + (size_t)(q0 + j * 8 + rin) * 64 + gg, (char*)QPs + j * 1024 + l * 16);
  }
  for (int jj = 0; jj < 2; jj++) {  // K/V tile 0 -> buf 0
    int j = w * 2 + jj;
    async16(Kg + (size_t)(j * 8 + rin) * 64 + gg, (char*)Ks + j * 1024 + l * 16);
    async16(Vg + (size_t)(j * 8 + rin) * Ln + gg, (char*)Vs + j * 1024 + l * 16);
  }
  __syncthreads();
  bfrag qf[2][2];  // wave-private rows, hoisted before P overwrites QPs
  for (int s = 0; s < 2; s++)
    for (int c = 0; c < 2; c++)
      qf[s][c] = fr8(QPs, w * 32 + s * 16 + lo, c * 4 + quad);

  facc o[2][4] = {};  // O^T[d = mi*16+quad*4+r][q = qset*16+lo]
  float l_i[2] = {0.f, 0.f};

  for (int t = 0; t < 32; t++) {  // full 2048 kpos
    const u16* Kc = Ks + (t & 1) * 4096;
    const u16* Vc = Vs + (t & 1) * 4096;
    if (t < 31) {  // prefetch next tile into other buffer
      int nb = (~t & 1) * 4096;
      int kbase = (t + 1) * 64;
      for (int jj = 0; jj < 2; jj++) {
        int j = w * 2 + jj;
        async16(Kg + (size_t)(kbase + j * 8 + rin) * 64 + gg,
                (char*)(Ks + nb) + j * 1024 + l * 16);
        async16(Vg + (size_t)(j * 8 + rin) * Ln + kbase + gg,
                (char*)(Vs + nb) + j * 1024 + l * 16);
      }
    }
    for (int ni = 0; ni < 4; ni++) {
      bfrag kf0 = fr8(Kc, ni * 16 + lo, quad);
      bfrag kf1 = fr8(Kc, ni * 16 + lo, 4 + quad);
      for (int s = 0; s < 2; s++) {
        facc z = {};
        facc stv = mfma16(kf1, qf[s][1], mfma16(kf0, qf[s][0], z));
        float p0 = __builtin_amdgcn_exp2f(stv[0]);
        float p1 = __builtin_amdgcn_exp2f(stv[1]);
        float p2 = __builtin_amdgcn_exp2f(stv[2]);
        float p3 = __builtin_amdgcn_exp2f(stv[3]);
        l_i[s] += (p0 + p1) + (p2 + p3);
        int row = w * 32 + s * 16 + lo;
        uint2 pk;
        pk.x = pkbf(p0, p1);
        pk.y = pkbf(p2, p3);
        int gi = ni * 2 + (quad >> 1);
        *(uint2*)&QPs[row * 64 + ((gi ^ (row & 7)) * 8) + (quad & 1) * 4] = pk;
      }
    }
    bfrag pb2[2][2];
    for (int s = 0; s < 2; s++)
      for (int c = 0; c < 2; c++)
        pb2[s][c] = fr8(QPs, w * 32 + s * 16 + lo, c * 4 + quad);
    for (int mi = 0; mi < 4; mi++) {
      bfrag vf0 = fr8(Vc, mi * 16 + lo, quad);
      bfrag vf1 = fr8(Vc, mi * 16 + lo, 4 + quad);
      for (int s = 0; s < 2; s++)
        o[s][mi] = mfma16(vf1, pb2[s][1], mfma16(vf0, pb2[s][0], o[s][mi]));
    }
    __syncthreads();
  }
  // epilogue: normalize and write yT [B,L,CI] directly (no partials)
  for (int s = 0; s < 2; s++) {
    float lt = l_i[s];
    lt += __shfl_xor(lt, 16);
    lt += __shfl_xor(lt, 32);
    float inv = 1.0f / lt;
    int q = q0 + w * 32 + s * 16 + lo;
    u16* dst = yT + ((size_t)b * Ln + q) * CIn + h * 64;
    for (int mi = 0; mi < 4; mi++) {
      uint2 pk;
      pk.x = pkbf(o[s][mi][0] * inv, o[s][mi][1] * inv);
      pk.y = pkbf(o[s][mi][2] * inv, o[s][mi][3] * inv);
      *(uint2*)(dst + mi * 16 + quad * 4) = pk;
    }
  }
}

// ---------------- kernel 4: W GEMM (64x128 tiles) + BN statistics ----------------
__global__ __launch_bounds__(256) void k_wgemm(
    const u16* __restrict__ Ww, const u16* __restrict__ yT,
    const float* __restrict__ wb, u16* __restrict__ wy,
    float* __restrict__ stats) {
  __shared__ __align__(16) u16 As[64 * 32];
  __shared__ __align__(16) u16 Bs[128 * 32];
  int w = threadIdx.x >> 6, l = threadIdx.x & 63;
  int quad = l >> 4, lo = l & 15;
  int m0 = blockIdx.y * 64, n0 = blockIdx.x * 128, b = blockIdx.z;
  facc acc[2][4] = {};
  gemm_core64(Ww + (size_t)m0 * CIn, yT + ((size_t)b * Ln + n0) * CIn, CIn, As, Bs, acc, w, l);
  int mw = (w >> 1) * 32, nw = (w & 1) * 64;
  for (int mi = 0; mi < 2; mi++) {
    int cb = m0 + mw + mi * 16 + quad * 4;
    for (int r = 0; r < 4; r++) {
      float bias = wb[cb + r];
      float s = 0.f, q = 0.f;
      for (int ni = 0; ni < 4; ni++) {
        float v = acc[mi][ni][r] + bias;
        wy[((size_t)b * Cn + cb + r) * Ln + n0 + nw + ni * 16 + lo] = f2bf_fast(v);
        s += v; q += v * v;  // stats from fp32 pre-round values
      }
      for (int mask = 1; mask < 16; mask <<= 1) {
        s += __shfl_xor(s, mask);
        q += __shfl_xor(q, mask);
      }
      if (lo == 0) {
        atomicAdd(&stats[cb + r], s);
        atomicAdd(&stats[Cn + cb + r], q);
      }
    }
  }
}

// ---------------- kernel 5: BN apply (bf16 in, f32 out) ----------------
__global__ void k_bn(const u16* __restrict__ wy, const float* __restrict__ stats,
                     const float* __restrict__ gam, const float* __restrict__ bet,
                     float* __restrict__ out) {
  int i = blockIdx.x * 256 + threadIdx.x;
  size_t idx = (size_t)i * 8;
  int c = (int)((idx >> 11) & (Cn - 1));  // [B,C,L], L=2^11
  const float invN = 1.f / (Bn * Ln);
  float mean = stats[c] * invN;
  float var = stats[Cn + c] * invN - mean * mean;
  float scl = gam[c] * rsqrtf(var + 1e-5f);
  float sh = bet[c] - mean * scl;
  uint4 v = *(const uint4*)(wy + idx);
  float4 o0, o1;
  o0.x = bflo(v.x) * scl + sh; o0.y = bfhi(v.x) * scl + sh;
  o0.z = bflo(v.y) * scl + sh; o0.w = bfhi(v.y) * scl + sh;
  o1.x = bflo(v.z) * scl + sh; o1.y = bfhi(v.z) * scl + sh;
  o1.z = bflo(v.w) * scl + sh; o1.w = bfhi(v.w) * scl + sh;
  *(float4*)(out + idx) = o0;
  *(float4*)(out + idx + 4) = o1;
}

extern "C" void kernel_launch(void* const* d_in, const int* in_sizes, int n_in,
                              void* d_out, int out_size, void* d_ws, size_t ws_size,
                              hipStream_t stream) {
  const float* x   = (const float*)d_in[0];
  const float* g_w = (const float*)d_in[1];
  const float* g_b = (const float*)d_in[2];
  const float* t_w = (const float*)d_in[3];
  const float* t_b = (const float*)d_in[4];
  const float* p_w = (const float*)d_in[5];
  const float* p_b = (const float*)d_in[6];
  const float* w_w = (const float*)d_in[7];
  const float* w_b = (const float*)d_in[8];
  const float* gam = (const float*)d_in[9];
  const float* bet = (const float*)d_in[10];
  float* out = (float*)d_out;

  char* ws = (char*)d_ws;
  size_t off = 0;
  auto alloc = [&](size_t bytes) {
    char* p = ws + off; off += (bytes + 255) & ~(size_t)255; return p;
  };
  u16*  xT   = (u16*)alloc((size_t)Bn * Ln * Cn * 2);      // x^T bf16        8.4MB
  u16*  Wcat = (u16*)alloc((size_t)COn * Cn * 2);          // [theta;phi;g]   1.6MB
  u16*  Ww   = (u16*)alloc((size_t)Cn * CIn * 2);          // w_w bf16        0.5MB
  u16*  Qb   = (u16*)alloc((size_t)Bn * Hn * Ln * Dn * 2); // theta [B,H,L,D] 8.4MB
  u16*  Kb   = (u16*)alloc((size_t)Bn * Hn * Ln * Dn * 2); // phi   [B,H,L,D] 8.4MB
  u16*  Vt   = (u16*)alloc((size_t)Bn * Hn * Dn * Ln * 2); // g     [B,H,D,L] 8.4MB
  u16*  yT   = (u16*)alloc((size_t)Bn * Ln * CIn * 2);     // attn out        8.4MB
  u16*  wy   = (u16*)alloc((size_t)Bn * Cn * Ln * 2);      // pre-BN bf16     8.4MB
  float* st  = (float*)alloc(2 * Cn * 4);                  // BN sum/sumsq
  if (ws_size < off) return;  // ~53 MB required

  k_misc<<<dim3(64, 16, 5), 256, 0, stream>>>(x, g_w, t_w, p_w, w_w, xT, Wcat, Ww, st);
  k_proj<<<dim3(16, 12, 4), 256, 0, stream>>>(Wcat, xT, t_b, p_b, g_b, Qb, Kb, Vt);
  k_attn<<<dim3(16, 8, 4), 256, 0, stream>>>(Qb, Kb, Vt, yT);
  k_wgemm<<<dim3(16, 8, 4), 256, 0, stream>>>(Ww, yT, w_b, wy, st);
  k_bn<<<dim3(2048), 256, 0, stream>>>(wy, st, gam, bet, out);
}